// Round 1
// baseline (382.785 us; speedup 1.0000x reference)
//
#include <hip/hip_runtime.h>
#include <stdint.h>

typedef __attribute__((ext_vector_type(8))) short short8;
typedef __attribute__((ext_vector_type(4))) float f32x4;
typedef unsigned short u16;

__device__ __forceinline__ u16 f2bf(float f) {
  union { float f; uint32_t u; } v; v.f = f;
  return (u16)((v.u + 0x7FFFu + ((v.u >> 16) & 1u)) >> 16);
}

__device__ __forceinline__ void gl_lds16(const void* g, void* l) {
  __builtin_amdgcn_global_load_lds(
      (const __attribute__((address_space(1))) void*)g,
      (__attribute__((address_space(3))) void*)l, 16, 0, 0);
}

// C[M,N] = A[M,K](bf16) @ B[N,K](bf16)^T  (+bias1+bias2)
// Writes f32 Cf and/or bf16 Cb (either may be null).
// M%128==0, N%128==0, K%32==0. m97 structure: 128x128 tile, 4 waves,
// global_load_lds width 16, 16x16x32 bf16 MFMA.
__global__ __launch_bounds__(256) void gemm_bt(
    const u16* __restrict__ A, const u16* __restrict__ B,
    float* __restrict__ Cf, u16* __restrict__ Cb,
    const float* __restrict__ bias1, const float* __restrict__ bias2,
    int M, int N, int K)
{
  __shared__ __align__(16) u16 As[128 * 32];
  __shared__ __align__(16) u16 Bs[128 * 32];
  const int t = threadIdx.x;
  const int lane = t & 63;
  const int w = t >> 6;
  const int wr = w >> 1, wc = w & 1;
  const int m0 = blockIdx.y * 128, n0 = blockIdx.x * 128;
  const int lr = lane & 15;
  const int lk = (lane >> 4) * 8;
  const int srow = t >> 2;          // staging row 0..63
  const int scol = (t & 3) * 8;     // staging col {0,8,16,24}

  const u16* gA = A + (size_t)(m0 + srow) * K + scol;
  const u16* gB = B + (size_t)(n0 + srow) * K + scol;

  f32x4 acc[4][4] = {};

  for (int k0 = 0; k0 < K; k0 += 32) {
    gl_lds16(gA,                  As + t * 8);
    gl_lds16(gA + (size_t)64 * K, As + 2048 + t * 8);
    gl_lds16(gB,                  Bs + t * 8);
    gl_lds16(gB + (size_t)64 * K, Bs + 2048 + t * 8);
    gA += 32; gB += 32;
    __syncthreads();   // compiler drains vmcnt before s_barrier

    short8 a[4], b[4];
#pragma unroll
    for (int m = 0; m < 4; ++m)
      a[m] = *(const short8*)(As + (wr * 64 + m * 16 + lr) * 32 + lk);
#pragma unroll
    for (int n = 0; n < 4; ++n)
      b[n] = *(const short8*)(Bs + (wc * 64 + n * 16 + lr) * 32 + lk);
#pragma unroll
    for (int m = 0; m < 4; ++m)
#pragma unroll
      for (int n = 0; n < 4; ++n)
        acc[m][n] = __builtin_amdgcn_mfma_f32_16x16x32_bf16(a[m], b[n], acc[m][n], 0, 0, 0);
    __syncthreads();
  }

  // C/D layout (verified m89/m91): col = lane&15, row = (lane>>4)*4 + reg
#pragma unroll
  for (int n = 0; n < 4; ++n) {
    int col = n0 + wc * 64 + n * 16 + lr;
    float bsum = 0.f;
    if (bias1) bsum += bias1[col];
    if (bias2) bsum += bias2[col];
#pragma unroll
    for (int m = 0; m < 4; ++m) {
#pragma unroll
      for (int r = 0; r < 4; ++r) {
        int row = m0 + wr * 64 + m * 16 + (lane >> 4) * 4 + r;
        float vv = acc[m][n][r] + bsum;
        if (Cf) Cf[(size_t)row * N + col] = vv;
        if (Cb) Cb[(size_t)row * N + col] = f2bf(vv);
      }
    }
  }
}

// f32 -> bf16 copy with output stride/offset (handles [A|B] concat packs)
__global__ __launch_bounds__(256) void cvt4_k(
    const float* __restrict__ in, u16* __restrict__ out,
    int n4, int cols, int ostride, int ooff)
{
  int i = blockIdx.x * 256 + threadIdx.x;
  if (i >= n4) return;
  int e = i * 4;
  int r = e / cols, cc = e - r * cols;
  float4 v = *(const float4*)(in + (size_t)e);
  ushort4 o; o.x = f2bf(v.x); o.y = f2bf(v.y); o.z = f2bf(v.z); o.w = f2bf(v.w);
  *(ushort4*)(out + (size_t)r * ostride + ooff + cc) = o;
}

// out[c*R + r] = bf16(in[r*C + c])  -- tiled transpose-convert (for Wk^T)
__global__ __launch_bounds__(256) void cvtT_k(
    const float* __restrict__ in, u16* __restrict__ out, int R, int C)
{
  __shared__ u16 tile[64][65];
  int tr = blockIdx.y * 64, tc = blockIdx.x * 64;
  int tx = threadIdx.x & 63;
  int ty = (threadIdx.x >> 6) * 16;
#pragma unroll
  for (int i = 0; i < 16; ++i)
    tile[ty + i][tx] = f2bf(in[(size_t)(tr + ty + i) * C + tc + tx]);
  __syncthreads();
#pragma unroll
  for (int i = 0; i < 16; ++i)
    out[(size_t)(tc + ty + i) * R + tr + tx] = tile[tx][ty + i];
}

// LSTM elementwise: gates (bias already added) + c -> h_new, c_new
__global__ __launch_bounds__(256) void lstm_k(
    const float* __restrict__ gates, const float* __restrict__ c,
    float* __restrict__ hnew, float* __restrict__ cnew)
{
  int i = blockIdx.x * 256 + threadIdx.x;     // exact: 2048*1024 threads
  int b = i >> 10, hh = i & 1023;
  const float* g = gates + (size_t)b * 4096;
  float ig = g[hh], fg = g[hh + 1024], gg = g[hh + 2048], og = g[hh + 3072];
  float si = 1.f / (1.f + expf(-ig));
  float sf = 1.f / (1.f + expf(-fg));
  float so = 1.f / (1.f + expf(-og));
  float cn = sf * c[i] + si * tanhf(gg);
  float hn = so * tanhf(cn);
  cnew[i] = cn;
  hnew[i] = hn;
}

// scores[b,m] = dot(Qk[b], memrow(b,m)) / 32 ; one wave per (b,m)
__global__ __launch_bounds__(256) void scores_k(
    const float* __restrict__ Qk, const float* __restrict__ mem,
    const float* __restrict__ hnew, float* __restrict__ scores)
{
  int wid = blockIdx.x * 4 + (threadIdx.x >> 6);   // b*64+m
  int lane = threadIdx.x & 63;
  int b = wid >> 6, m = wid & 63;
  const float* row = (m < 63) ? (mem + ((size_t)b * 64 + m + 1) * 1024)
                              : (hnew + (size_t)b * 1024);
  const float* q = Qk + (size_t)b * 1024;
  float s = 0.f;
#pragma unroll
  for (int it = 0; it < 4; ++it) {
    int j = (it * 64 + lane) * 4;
    float4 v = *(const float4*)(row + j);
    float4 qv = *(const float4*)(q + j);
    s += v.x * qv.x + v.y * qv.y + v.z * qv.z + v.w * qv.w;
  }
#pragma unroll
  for (int off = 32; off; off >>= 1) s += __shfl_down(s, off);
  if (lane == 0) scores[wid] = s * 0.03125f;
}

// softmax over m=64 ; one wave per b
__global__ __launch_bounds__(256) void softmax_k(
    const float* __restrict__ scores, float* __restrict__ attn)
{
  int b = blockIdx.x * 4 + (threadIdx.x >> 6);
  int lane = threadIdx.x & 63;
  float s = scores[(size_t)b * 64 + lane];
  float mx = s;
#pragma unroll
  for (int off = 32; off; off >>= 1) mx = fmaxf(mx, __shfl_xor(mx, off));
  float e = expf(s - mx);
  float sum = e;
#pragma unroll
  for (int off = 32; off; off >>= 1) sum += __shfl_xor(sum, off);
  attn[(size_t)b * 64 + lane] = e / sum;
}

// ctx[b,:] = sum_m attn[b,m] * memrow(b,m), written as bf16 ; one block per b
__global__ __launch_bounds__(256) void ctx_k(
    const float* __restrict__ attn, const float* __restrict__ mem,
    const float* __restrict__ hnew, u16* __restrict__ ctxb)
{
  int b = blockIdx.x;
  int t = threadIdx.x;
  __shared__ float a[64];
  if (t < 64) a[t] = attn[(size_t)b * 64 + t];
  __syncthreads();
  int h0 = t * 4;
  const float* mb = mem + (size_t)b * 64 * 1024;
  float x = 0.f, y = 0.f, z = 0.f, u = 0.f;
#pragma unroll 4
  for (int m = 0; m < 63; ++m) {
    float4 v = *(const float4*)(mb + (size_t)(m + 1) * 1024 + h0);
    float wg = a[m];
    x += wg * v.x; y += wg * v.y; z += wg * v.z; u += wg * v.w;
  }
  {
    float4 v = *(const float4*)(hnew + (size_t)b * 1024 + h0);
    float wg = a[63];
    x += wg * v.x; y += wg * v.y; z += wg * v.z; u += wg * v.w;
  }
  ushort4 o; o.x = f2bf(x); o.y = f2bf(y); o.z = f2bf(z); o.w = f2bf(u);
  *(ushort4*)(ctxb + (size_t)b * 1024 + h0) = o;
}

extern "C" void kernel_launch(void* const* d_in, const int* in_sizes, int n_in,
                              void* d_out, int out_size, void* d_ws, size_t ws_size,
                              hipStream_t stream) {
  const int Bb = 2048, Hh = 1024;
  const float* pose  = (const float*)d_in[0];
  const float* query = (const float*)d_in[1];
  const float* h     = (const float*)d_in[2];
  const float* c     = (const float*)d_in[3];
  const float* mem   = (const float*)d_in[4];
  const float* W_ih  = (const float*)d_in[5];
  const float* W_hh  = (const float*)d_in[6];
  const float* b_ih  = (const float*)d_in[7];
  const float* b_hh  = (const float*)d_in[8];
  const float* Wq    = (const float*)d_in[9];
  const float* bq    = (const float*)d_in[10];
  const float* Wk    = (const float*)d_in[11];
  // d_in[12] = bk: cancels in softmax (m-independent shift), unused
  const float* Wv    = (const float*)d_in[13];
  const float* bv    = (const float*)d_in[14];

  float* out_att = (float*)d_out;                       // [2048,1024]
  float* out_h   = out_att + (size_t)Bb * Hh;           // [2048,1024]
  float* out_c   = out_h + (size_t)Bb * Hh;             // [2048,1024]

  // workspace layout (~83 MiB total)
  char* wp = (char*)d_ws;
  auto alloc = [&](size_t bytes) {
    char* p = wp; wp += (bytes + 255) & ~(size_t)255; return p;
  };
  u16*   Xcat  = (u16*)alloc((size_t)2048 * 2048 * 2);  // [pose|h] bf16
  u16*   Wcat  = (u16*)alloc((size_t)4096 * 2048 * 2);  // [W_ih|W_hh] bf16
  u16*   Qryb  = (u16*)alloc((size_t)2048 * 1024 * 2);
  u16*   Wqb   = (u16*)alloc((size_t)1024 * 1024 * 2);
  u16*   WkTb  = (u16*)alloc((size_t)1024 * 1024 * 2);
  u16*   Wvb   = (u16*)alloc((size_t)1024 * 1024 * 2);
  float* gates = (float*)alloc((size_t)2048 * 4096 * 4);
  u16*   Qbf   = (u16*)alloc((size_t)2048 * 1024 * 2);
  float* Qk    = (float*)alloc((size_t)2048 * 1024 * 4);
  float* scor  = (float*)alloc((size_t)2048 * 64 * 4);
  float* attn  = (float*)alloc((size_t)2048 * 64 * 4);
  u16*   ctxb  = (u16*)alloc((size_t)2048 * 1024 * 2);

  // --- conversions to bf16 ---
  cvt4_k<<<2048, 256, 0, stream>>>(pose,  Xcat, 2048 * 1024 / 4, 1024, 2048, 0);
  cvt4_k<<<2048, 256, 0, stream>>>(h,     Xcat, 2048 * 1024 / 4, 1024, 2048, 1024);
  cvt4_k<<<4096, 256, 0, stream>>>(W_ih,  Wcat, 4096 * 1024 / 4, 1024, 2048, 0);
  cvt4_k<<<4096, 256, 0, stream>>>(W_hh,  Wcat, 4096 * 1024 / 4, 1024, 2048, 1024);
  cvt4_k<<<2048, 256, 0, stream>>>(query, Qryb, 2048 * 1024 / 4, 1024, 1024, 0);
  cvt4_k<<<1024, 256, 0, stream>>>(Wq,    Wqb,  1024 * 1024 / 4, 1024, 1024, 0);
  cvt4_k<<<1024, 256, 0, stream>>>(Wv,    Wvb,  1024 * 1024 / 4, 1024, 1024, 0);
  cvtT_k<<<dim3(16, 16), 256, 0, stream>>>(Wk, WkTb, 1024, 1024);

  // --- gates = [pose|h] @ [W_ih|W_hh]^T + b_ih + b_hh  (2048x4096, K=2048) ---
  gemm_bt<<<dim3(4096 / 128, 2048 / 128), 256, 0, stream>>>(
      Xcat, Wcat, gates, nullptr, b_ih, b_hh, 2048, 4096, 2048);

  // --- LSTM elementwise -> h_new, c_new (straight into d_out) ---
  lstm_k<<<8192, 256, 0, stream>>>(gates, c, out_h, out_c);

  // --- Q = query @ Wq^T + bq  (bf16 out) ---
  gemm_bt<<<dim3(1024 / 128, 2048 / 128), 256, 0, stream>>>(
      Qryb, Wqb, nullptr, Qbf, bq, nullptr, 2048, 1024, 1024);

  // --- Qk = Q @ Wk  (f32 out; bk dropped: softmax-shift-invariant) ---
  gemm_bt<<<dim3(1024 / 128, 2048 / 128), 256, 0, stream>>>(
      Qbf, WkTb, Qk, nullptr, nullptr, nullptr, 2048, 1024, 1024);

  // --- attention over FIFO memory (rows 1..63 of memory, then h_new) ---
  scores_k<<<2048 * 64 / 4, 256, 0, stream>>>(Qk, mem, out_h, scor);
  softmax_k<<<2048 / 4, 256, 0, stream>>>(scor, attn);
  ctx_k<<<2048, 256, 0, stream>>>(attn, mem, out_h, ctxb);

  // --- attended = ctx @ Wv^T + bv  -> d_out ---
  gemm_bt<<<dim3(1024 / 128, 2048 / 128), 256, 0, stream>>>(
      ctxb, Wvb, out_att, nullptr, bv, nullptr, 2048, 1024, 1024);
}

// Round 2
// 295.798 us; speedup vs baseline: 1.2941x; 1.2941x over previous
//
#include <hip/hip_runtime.h>
#include <stdint.h>

typedef __attribute__((ext_vector_type(8))) short short8;
typedef __attribute__((ext_vector_type(4))) float f32x4;
typedef unsigned short u16;

__device__ __forceinline__ u16 f2bf(float f) {
  union { float f; uint32_t u; } v; v.f = f;
  return (u16)((v.u + 0x7FFFu + ((v.u >> 16) & 1u)) >> 16);
}

__device__ __forceinline__ void gl_lds16(const void* g, void* l) {
  __builtin_amdgcn_global_load_lds(
      (const __attribute__((address_space(1))) void*)g,
      (__attribute__((address_space(3))) void*)l, 16, 0, 0);
}

// C[M,N] = A[M,K](bf16) @ B[N,K](bf16)^T  (+bias1+bias2)
// Writes f32 Cf and/or bf16 Cb (either may be null).
// M%128==0, N%128==0, K%32==0. m97 structure.
__global__ __launch_bounds__(256) void gemm_bt(
    const u16* __restrict__ A, const u16* __restrict__ B,
    float* __restrict__ Cf, u16* __restrict__ Cb,
    const float* __restrict__ bias1, const float* __restrict__ bias2,
    int M, int N, int K)
{
  __shared__ __align__(16) u16 As[128 * 32];
  __shared__ __align__(16) u16 Bs[128 * 32];
  const int t = threadIdx.x;
  const int lane = t & 63;
  const int w = t >> 6;
  const int wr = w >> 1, wc = w & 1;
  const int m0 = blockIdx.y * 128, n0 = blockIdx.x * 128;
  const int lr = lane & 15;
  const int lk = (lane >> 4) * 8;
  const int srow = t >> 2;
  const int scol = (t & 3) * 8;

  const u16* gA = A + (size_t)(m0 + srow) * K + scol;
  const u16* gB = B + (size_t)(n0 + srow) * K + scol;

  f32x4 acc[4][4] = {};

  for (int k0 = 0; k0 < K; k0 += 32) {
    gl_lds16(gA,                  As + t * 8);
    gl_lds16(gA + (size_t)64 * K, As + 2048 + t * 8);
    gl_lds16(gB,                  Bs + t * 8);
    gl_lds16(gB + (size_t)64 * K, Bs + 2048 + t * 8);
    gA += 32; gB += 32;
    __syncthreads();

    short8 a[4], b[4];
#pragma unroll
    for (int m = 0; m < 4; ++m)
      a[m] = *(const short8*)(As + (wr * 64 + m * 16 + lr) * 32 + lk);
#pragma unroll
    for (int n = 0; n < 4; ++n)
      b[n] = *(const short8*)(Bs + (wc * 64 + n * 16 + lr) * 32 + lk);
#pragma unroll
    for (int m = 0; m < 4; ++m)
#pragma unroll
      for (int n = 0; n < 4; ++n)
        acc[m][n] = __builtin_amdgcn_mfma_f32_16x16x32_bf16(a[m], b[n], acc[m][n], 0, 0, 0);
    __syncthreads();
  }

  // C/D layout (m89/m91): col = lane&15, row = (lane>>4)*4 + reg
#pragma unroll
  for (int n = 0; n < 4; ++n) {
    int col = n0 + wc * 64 + n * 16 + lr;
    float bsum = 0.f;
    if (bias1) bsum += bias1[col];
    if (bias2) bsum += bias2[col];
#pragma unroll
    for (int m = 0; m < 4; ++m) {
#pragma unroll
      for (int r = 0; r < 4; ++r) {
        int row = m0 + wr * 64 + m * 16 + (lane >> 4) * 4 + r;
        float vv = acc[m][n][r] + bsum;
        if (Cf) Cf[(size_t)row * N + col] = vv;
        if (Cb) Cb[(size_t)row * N + col] = f2bf(vv);
      }
    }
  }
}

// All f32->bf16 packs in ONE kernel. Segments by blockIdx (1024 elems/block).
// All sources have 1024 columns.
__global__ __launch_bounds__(256) void packall_k(
    const float* __restrict__ p0, const float* __restrict__ p1,
    const float* __restrict__ p2, const float* __restrict__ p3,
    const float* __restrict__ p4, const float* __restrict__ p5,
    u16* __restrict__ xcat, u16* __restrict__ wcat,
    u16* __restrict__ qry, u16* __restrict__ wv)
{
  int blk = blockIdx.x;
  const float* src; u16* dst; int ostride, ooff, base;
  if (blk < 2048)       { src = p0; dst = xcat; ostride = 2048; ooff = 0;    base = 0; }
  else if (blk < 4096)  { src = p1; dst = xcat; ostride = 2048; ooff = 1024; base = 2048; }
  else if (blk < 8192)  { src = p2; dst = wcat; ostride = 2048; ooff = 0;    base = 4096; }
  else if (blk < 12288) { src = p3; dst = wcat; ostride = 2048; ooff = 1024; base = 8192; }
  else if (blk < 14336) { src = p4; dst = qry;  ostride = 1024; ooff = 0;    base = 12288; }
  else                  { src = p5; dst = wv;   ostride = 1024; ooff = 0;    base = 14336; }
  int e = (blk - base) * 1024 + threadIdx.x * 4;
  int r = e >> 10, cc = e & 1023;
  float4 v = *(const float4*)(src + (size_t)e);
  ushort4 o; o.x = f2bf(v.x); o.y = f2bf(v.y); o.z = f2bf(v.z); o.w = f2bf(v.w);
  *(ushort4*)(dst + (size_t)r * ostride + ooff + cc) = o;
}

// out[c*R + r] = bf16(in[r*C + c])  -- tiled transpose-convert
__global__ __launch_bounds__(256) void cvtT_k(
    const float* __restrict__ in, u16* __restrict__ out, int R, int C)
{
  __shared__ u16 tile[64][65];
  int tr = blockIdx.y * 64, tc = blockIdx.x * 64;
  int tx = threadIdx.x & 63;
  int ty = (threadIdx.x >> 6) * 16;
#pragma unroll
  for (int i = 0; i < 16; ++i)
    tile[ty + i][tx] = f2bf(in[(size_t)(tr + ty + i) * C + tc + tx]);
  __syncthreads();
#pragma unroll
  for (int i = 0; i < 16; ++i)
    out[(size_t)(tc + ty + i) * R + tr + tx] = tile[tx][ty + i];
}

// qkb[n] += sum_{j in block.y chunk} bq[j] * Wk[j*1024+n]   (qkb pre-zeroed)
__global__ __launch_bounds__(256) void bqwk_k(
    const float* __restrict__ bq, const float* __restrict__ Wk,
    float* __restrict__ qkb)
{
  int n = blockIdx.x * 256 + threadIdx.x;
  int j0 = blockIdx.y * 64;
  float s = 0.f;
#pragma unroll 8
  for (int j = j0; j < j0 + 64; ++j) s += bq[j] * Wk[(size_t)j * 1024 + n];
  atomicAdd(&qkb[n], s);
}

// LSTM elementwise (fast sigmoid/tanh via v_exp)
__global__ __launch_bounds__(256) void lstm_k(
    const float* __restrict__ gates, const float* __restrict__ c,
    float* __restrict__ hnew, float* __restrict__ cnew)
{
  int i = blockIdx.x * 256 + threadIdx.x;
  int b = i >> 10, hh = i & 1023;
  const float* g = gates + (size_t)b * 4096;
  float ig = g[hh], fg = g[hh + 1024], gg = g[hh + 2048], og = g[hh + 3072];
  float si = 1.f / (1.f + __expf(-ig));
  float sf = 1.f / (1.f + __expf(-fg));
  float so = 1.f / (1.f + __expf(-og));
  float tg = 2.f / (1.f + __expf(-2.f * gg)) - 1.f;
  float cn = sf * c[i] + si * tg;
  float tc2 = 2.f / (1.f + __expf(-2.f * cn)) - 1.f;
  float hn = so * tc2;
  cnew[i] = cn;
  hnew[i] = hn;
}

// row dot: fills rv[4] with the row, returns dot(row, qv)/32 (all lanes)
__device__ __forceinline__ float rowdot(const float* __restrict__ row,
                                        const float4* qv, int lane, float4* rv) {
  float s = 0.f;
#pragma unroll
  for (int i = 0; i < 4; ++i) {
    rv[i] = *(const float4*)(row + (i * 64 + lane) * 4);
    s += rv[i].x * qv[i].x + rv[i].y * qv[i].y + rv[i].z * qv[i].z + rv[i].w * qv[i].w;
  }
#pragma unroll
  for (int off = 32; off; off >>= 1) s += __shfl_xor(s, off);
  return s * 0.03125f;  // 1/sqrt(1024)
}

// Fused single-pass attention: scores + online softmax (defer-max THR=8) + ctx.
// One wave per batch row b. mem rows 1..63 then h_new as the newest row.
__global__ __launch_bounds__(256) void attn_fused_k(
    const float* __restrict__ Qk, const float* __restrict__ mem,
    const float* __restrict__ hnew, u16* __restrict__ ctxb)
{
  int b = blockIdx.x * 4 + (threadIdx.x >> 6);
  int lane = threadIdx.x & 63;
  const float* q = Qk + (size_t)b * 1024;
  float4 qv[4];
#pragma unroll
  for (int i = 0; i < 4; ++i) qv[i] = *(const float4*)(q + (i * 64 + lane) * 4);

  const float* mb = mem + (size_t)b * 65536;
  float4 rv[4], cx[4];
  float m_run = rowdot(mb + 1024, qv, lane, rv);   // m=0 -> memory row 1
  float l = 1.f;
#pragma unroll
  for (int i = 0; i < 4; ++i) cx[i] = rv[i];

  for (int mm = 1; mm < 64; ++mm) {
    const float* row = (mm < 63) ? (mb + (size_t)(mm + 1) * 1024)
                                 : (hnew + (size_t)b * 1024);
    float s = rowdot(row, qv, lane, rv);
    if (s <= m_run + 8.f) {          // defer-max: no rescale (the common path)
      float e = __expf(s - m_run);
      l += e;
#pragma unroll
      for (int i = 0; i < 4; ++i) {
        cx[i].x += e * rv[i].x; cx[i].y += e * rv[i].y;
        cx[i].z += e * rv[i].z; cx[i].w += e * rv[i].w;
      }
    } else {                          // rare: new max exceeds threshold
      float sc = __expf(m_run - s);
      m_run = s;
      l = l * sc + 1.f;
#pragma unroll
      for (int i = 0; i < 4; ++i) {
        cx[i].x = cx[i].x * sc + rv[i].x; cx[i].y = cx[i].y * sc + rv[i].y;
        cx[i].z = cx[i].z * sc + rv[i].z; cx[i].w = cx[i].w * sc + rv[i].w;
      }
    }
  }
  float inv = 1.f / l;
#pragma unroll
  for (int i = 0; i < 4; ++i) {
    ushort4 o;
    o.x = f2bf(cx[i].x * inv); o.y = f2bf(cx[i].y * inv);
    o.z = f2bf(cx[i].z * inv); o.w = f2bf(cx[i].w * inv);
    *(ushort4*)(ctxb + (size_t)b * 1024 + (i * 64 + lane) * 4) = o;
  }
}

extern "C" void kernel_launch(void* const* d_in, const int* in_sizes, int n_in,
                              void* d_out, int out_size, void* d_ws, size_t ws_size,
                              hipStream_t stream) {
  const int Bb = 2048, Hh = 1024;
  const float* pose  = (const float*)d_in[0];
  const float* query = (const float*)d_in[1];
  const float* h     = (const float*)d_in[2];
  const float* c     = (const float*)d_in[3];
  const float* mem   = (const float*)d_in[4];
  const float* W_ih  = (const float*)d_in[5];
  const float* W_hh  = (const float*)d_in[6];
  const float* b_ih  = (const float*)d_in[7];
  const float* b_hh  = (const float*)d_in[8];
  const float* Wq    = (const float*)d_in[9];
  const float* bq    = (const float*)d_in[10];
  const float* Wk    = (const float*)d_in[11];
  // d_in[12] = bk: m-independent shift, cancels in softmax
  const float* Wv    = (const float*)d_in[13];
  const float* bv    = (const float*)d_in[14];

  float* out_att = (float*)d_out;
  float* out_h   = out_att + (size_t)Bb * Hh;
  float* out_c   = out_h + (size_t)Bb * Hh;

  char* wp = (char*)d_ws;
  auto alloc = [&](size_t bytes) {
    char* p = wp; wp += (bytes + 255) & ~(size_t)255; return p;
  };
  u16*   Xcat  = (u16*)alloc((size_t)2048 * 2048 * 2);
  u16*   Wcat  = (u16*)alloc((size_t)4096 * 2048 * 2);
  u16*   Qryb  = (u16*)alloc((size_t)2048 * 1024 * 2);
  u16*   WqTb  = (u16*)alloc((size_t)1024 * 1024 * 2);
  u16*   WkTb  = (u16*)alloc((size_t)1024 * 1024 * 2);
  u16*   Wvb   = (u16*)alloc((size_t)1024 * 1024 * 2);
  u16*   Wqk2b = (u16*)alloc((size_t)1024 * 1024 * 2);
  float* gates = (float*)alloc((size_t)2048 * 4096 * 4);
  float* qkb   = (float*)alloc((size_t)1024 * 4);
  float* Qk    = (float*)alloc((size_t)2048 * 1024 * 4);
  u16*   ctxb  = (u16*)alloc((size_t)2048 * 1024 * 2);

  // --- conversions (3 launches) ---
  packall_k<<<15360, 256, 0, stream>>>(pose, h, W_ih, W_hh, query, Wv,
                                       Xcat, Wcat, Qryb, Wvb);
  cvtT_k<<<dim3(16, 16), 256, 0, stream>>>(Wq, WqTb, 1024, 1024);
  cvtT_k<<<dim3(16, 16), 256, 0, stream>>>(Wk, WkTb, 1024, 1024);

  // --- qkb = bq @ Wk  (f32, tiny) ---
  hipMemsetAsync(qkb, 0, 1024 * sizeof(float), stream);
  bqwk_k<<<dim3(4, 16), 256, 0, stream>>>(bq, Wk, qkb);

  // --- Wqk2[a,b] = sum_j Wk[j,a] * Wq[j,b]  (bf16 out) ---
  gemm_bt<<<dim3(8, 8), 256, 0, stream>>>(
      WkTb, WqTb, nullptr, Wqk2b, nullptr, nullptr, 1024, 1024, 1024);

  // --- gates = [pose|h] @ [W_ih|W_hh]^T + b_ih + b_hh ---
  gemm_bt<<<dim3(32, 16), 256, 0, stream>>>(
      Xcat, Wcat, gates, nullptr, b_ih, b_hh, 2048, 4096, 2048);

  // --- LSTM elementwise -> h_new, c_new ---
  lstm_k<<<8192, 256, 0, stream>>>(gates, c, out_h, out_c);

  // --- Qk = query @ Wqk2^T + qkb  (== (query@Wq^T + bq) @ Wk) ---
  gemm_bt<<<dim3(8, 16), 256, 0, stream>>>(
      Qryb, Wqk2b, Qk, nullptr, qkb, nullptr, 2048, 1024, 1024);

  // --- fused scores + softmax + ctx (single pass over memory) ---
  attn_fused_k<<<512, 256, 0, stream>>>(Qk, mem, out_h, ctxb);

  // --- attended = ctx @ Wv^T + bv ---
  gemm_bt<<<dim3(8, 16), 256, 0, stream>>>(
      ctxb, Wvb, out_att, nullptr, bv, nullptr, 2048, 1024, 1024);
}

// Round 3
// 264.206 us; speedup vs baseline: 1.4488x; 1.1196x over previous
//
#include <hip/hip_runtime.h>
#include <stdint.h>

typedef __attribute__((ext_vector_type(8))) short short8;
typedef __attribute__((ext_vector_type(4))) float f32x4;
typedef unsigned short u16;

__device__ __forceinline__ u16 f2bf(float f) {
  union { float f; uint32_t u; } v; v.f = f;
  return (u16)((v.u + 0x7FFFu + ((v.u >> 16) & 1u)) >> 16);
}

__device__ __forceinline__ void gl_lds16(const void* g, void* l) {
  __builtin_amdgcn_global_load_lds(
      (const __attribute__((address_space(1))) void*)g,
      (__attribute__((address_space(3))) void*)l, 16, 0, 0);
}

// ---------------- generic small GEMM (m97 structure) ----------------
// C[M,N] = A[M,K](bf16) @ B[N,K](bf16)^T (+bias); f32 and/or bf16 out.
__global__ __launch_bounds__(256) void gemm_bt(
    const u16* __restrict__ A, const u16* __restrict__ B,
    float* __restrict__ Cf, u16* __restrict__ Cb,
    const float* __restrict__ bias1,
    int M, int N, int K)
{
  __shared__ __align__(16) u16 As[128 * 32];
  __shared__ __align__(16) u16 Bs[128 * 32];
  const int t = threadIdx.x;
  const int lane = t & 63;
  const int w = t >> 6;
  const int wr = w >> 1, wc = w & 1;
  const int m0 = blockIdx.y * 128, n0 = blockIdx.x * 128;
  const int lr = lane & 15;
  const int lk = (lane >> 4) * 8;
  const int srow = t >> 2;
  const int scol = (t & 3) * 8;

  const u16* gA = A + (size_t)(m0 + srow) * K + scol;
  const u16* gB = B + (size_t)(n0 + srow) * K + scol;

  f32x4 acc[4][4] = {};

  for (int k0 = 0; k0 < K; k0 += 32) {
    gl_lds16(gA,                  As + t * 8);
    gl_lds16(gA + (size_t)64 * K, As + 2048 + t * 8);
    gl_lds16(gB,                  Bs + t * 8);
    gl_lds16(gB + (size_t)64 * K, Bs + 2048 + t * 8);
    gA += 32; gB += 32;
    __syncthreads();

    short8 a[4], b[4];
#pragma unroll
    for (int m = 0; m < 4; ++m)
      a[m] = *(const short8*)(As + (wr * 64 + m * 16 + lr) * 32 + lk);
#pragma unroll
    for (int n = 0; n < 4; ++n)
      b[n] = *(const short8*)(Bs + (wc * 64 + n * 16 + lr) * 32 + lk);
#pragma unroll
    for (int m = 0; m < 4; ++m)
#pragma unroll
      for (int n = 0; n < 4; ++n)
        acc[m][n] = __builtin_amdgcn_mfma_f32_16x16x32_bf16(a[m], b[n], acc[m][n], 0, 0, 0);
    __syncthreads();
  }

#pragma unroll
  for (int n = 0; n < 4; ++n) {
    int col = n0 + wc * 64 + n * 16 + lr;
    float bsum = bias1 ? bias1[col] : 0.f;
#pragma unroll
    for (int m = 0; m < 4; ++m) {
#pragma unroll
      for (int r = 0; r < 4; ++r) {
        int row = m0 + wr * 64 + m * 16 + (lane >> 4) * 4 + r;
        float vv = acc[m][n][r] + bsum;
        if (Cf) Cf[(size_t)row * N + col] = vv;
        if (Cb) Cb[(size_t)row * N + col] = f2bf(vv);
      }
    }
  }
}

// ---------------- prep: all f32->bf16 packs + Wk transpose ----------------
__global__ __launch_bounds__(256) void prep_k(
    const float* __restrict__ pose, const float* __restrict__ h,
    const float* __restrict__ W_ih, const float* __restrict__ W_hh,
    const float* __restrict__ query, const float* __restrict__ Wv,
    const float* __restrict__ Wq, const float* __restrict__ Wk,
    u16* __restrict__ xcat, u16* __restrict__ wcat,
    u16* __restrict__ qry, u16* __restrict__ wvb,
    u16* __restrict__ wqb, u16* __restrict__ wktb)
{
  __shared__ u16 tile[64][65];
  int blk = blockIdx.x;
  int t = threadIdx.x;
  if (blk >= 16384) {  // Wk transpose-convert: wktb[n*1024+a] = bf16(Wk[a*1024+n])
    int tblk = blk - 16384;
    int tr = (tblk >> 4) * 64, tc = (tblk & 15) * 64;
    int tx = t & 63;
    int ty = (t >> 6) * 16;
#pragma unroll
    for (int i = 0; i < 16; ++i)
      tile[ty + i][tx] = f2bf(Wk[(size_t)(tr + ty + i) * 1024 + tc + tx]);
    __syncthreads();
#pragma unroll
    for (int i = 0; i < 16; ++i)
      wktb[(size_t)(tc + ty + i) * 1024 + tr + tx] = tile[tx][ty + i];
    return;
  }
  const float* src; u16* dst; int ostride, ooff, base;
  if (blk < 2048)       { src = pose;  dst = xcat; ostride = 2048; ooff = 0;    base = 0; }
  else if (blk < 4096)  { src = h;     dst = xcat; ostride = 2048; ooff = 1024; base = 2048; }
  else if (blk < 8192)  { src = W_ih;  dst = wcat; ostride = 2048; ooff = 0;    base = 4096; }
  else if (blk < 12288) { src = W_hh;  dst = wcat; ostride = 2048; ooff = 1024; base = 8192; }
  else if (blk < 14336) { src = query; dst = qry;  ostride = 1024; ooff = 0;    base = 12288; }
  else if (blk < 15360) { src = Wv;    dst = wvb;  ostride = 1024; ooff = 0;    base = 14336; }
  else                  { src = Wq;    dst = wqb;  ostride = 1024; ooff = 0;    base = 15360; }
  int r = blk - base;
  int cc = t * 4;
  float4 v = *(const float4*)(src + (size_t)r * 1024 + cc);
  ushort4 o; o.x = f2bf(v.x); o.y = f2bf(v.y); o.z = f2bf(v.z); o.w = f2bf(v.w);
  *(ushort4*)(dst + (size_t)r * ostride + ooff + cc) = o;
}

// ---------------- mega: gates GEMM blocks + attention-partial blocks --------
// 768 blocks: blk%3 in {0,1} -> gates gemm (512 tiles), blk%3==2 -> attn (256).
__global__ __launch_bounds__(256, 3) void mega_k(
    const u16* __restrict__ Xcat, const u16* __restrict__ Wcat,
    float* __restrict__ gates,
    const float* __restrict__ b_ih, const float* __restrict__ b_hh,
    const float* __restrict__ Qk, const float* __restrict__ mem,
    float* __restrict__ attst)
{
  __shared__ __align__(16) u16 As[128 * 32];
  __shared__ __align__(16) u16 Bs[128 * 32];
  const int blk = blockIdx.x;
  const int t = threadIdx.x;
  const int lane = t & 63;

  if (blk % 3 != 2) {
    // ---- gates GEMM tile: M=2048 N=4096 K=2048 ----
    const int gid = (blk / 3) * 2 + (blk % 3);      // 0..511
    const int m0 = (gid >> 5) * 128, n0 = (gid & 31) * 128;
    const int w = t >> 6;
    const int wr = w >> 1, wc = w & 1;
    const int lr = lane & 15;
    const int lk = (lane >> 4) * 8;
    const int srow = t >> 2;
    const int scol = (t & 3) * 8;

    const u16* gA = Xcat + (size_t)(m0 + srow) * 2048 + scol;
    const u16* gB = Wcat + (size_t)(n0 + srow) * 2048 + scol;

    f32x4 acc[4][4] = {};
    for (int k0 = 0; k0 < 2048; k0 += 32) {
      gl_lds16(gA,                    As + t * 8);
      gl_lds16(gA + (size_t)64 * 2048, As + 2048 + t * 8);
      gl_lds16(gB,                    Bs + t * 8);
      gl_lds16(gB + (size_t)64 * 2048, Bs + 2048 + t * 8);
      gA += 32; gB += 32;
      __syncthreads();
      short8 a[4], b[4];
#pragma unroll
      for (int m = 0; m < 4; ++m)
        a[m] = *(const short8*)(As + (wr * 64 + m * 16 + lr) * 32 + lk);
#pragma unroll
      for (int n = 0; n < 4; ++n)
        b[n] = *(const short8*)(Bs + (wc * 64 + n * 16 + lr) * 32 + lk);
#pragma unroll
      for (int m = 0; m < 4; ++m)
#pragma unroll
        for (int n = 0; n < 4; ++n)
          acc[m][n] = __builtin_amdgcn_mfma_f32_16x16x32_bf16(a[m], b[n], acc[m][n], 0, 0, 0);
      __syncthreads();
    }
#pragma unroll
    for (int n = 0; n < 4; ++n) {
      int col = n0 + wc * 64 + n * 16 + lr;
      float bsum = b_ih[col] + b_hh[col];
#pragma unroll
      for (int m = 0; m < 4; ++m)
#pragma unroll
        for (int r = 0; r < 4; ++r) {
          int row = m0 + wr * 64 + m * 16 + (lane >> 4) * 4 + r;
          gates[(size_t)row * 4096 + col] = acc[m][n][r] + bsum;
        }
    }
  } else {
    // ---- attention partial over memory rows 1..63 (online softmax) ----
    const int ablk = blk / 3;                        // 0..255
    const int wv_id = t >> 6;
    for (int bi = 0; bi < 2; ++bi) {
      const int b = ablk * 8 + wv_id * 2 + bi;
      const float* q = Qk + (size_t)b * 1024;
      float4 qv[4];
#pragma unroll
      for (int i = 0; i < 4; ++i)
        qv[i] = *(const float4*)(q + (i * 64 + lane) * 4);
      const float* mb = mem + (size_t)b * 65536;

      float m_run = -3e38f, l = 0.f;
      float4 cx[4] = {};

      // 15 quads: rows 1..60
      for (int qd = 0; qd < 15; ++qd) {
        const float* r0 = mb + (size_t)(1 + qd * 4) * 1024;
        float4 rv[4][4];
        float s[4] = {0.f, 0.f, 0.f, 0.f};
#pragma unroll
        for (int rr = 0; rr < 4; ++rr)
#pragma unroll
          for (int i = 0; i < 4; ++i) {
            rv[rr][i] = *(const float4*)(r0 + rr * 1024 + (i * 64 + lane) * 4);
            s[rr] += rv[rr][i].x * qv[i].x + rv[rr][i].y * qv[i].y +
                     rv[rr][i].z * qv[i].z + rv[rr][i].w * qv[i].w;
          }
#pragma unroll
        for (int rr = 0; rr < 4; ++rr) {
#pragma unroll
          for (int off = 32; off; off >>= 1) s[rr] += __shfl_xor(s[rr], off);
          s[rr] *= 0.03125f;
        }
#pragma unroll
        for (int rr = 0; rr < 4; ++rr) {
          if (s[rr] <= m_run + 8.f) {
            float e = __expf(s[rr] - m_run);
            l += e;
#pragma unroll
            for (int i = 0; i < 4; ++i) {
              cx[i].x += e * rv[rr][i].x; cx[i].y += e * rv[rr][i].y;
              cx[i].z += e * rv[rr][i].z; cx[i].w += e * rv[rr][i].w;
            }
          } else {
            float sc = __expf(m_run - s[rr]);
            m_run = s[rr];
            l = l * sc + 1.f;
#pragma unroll
            for (int i = 0; i < 4; ++i) {
              cx[i].x = cx[i].x * sc + rv[rr][i].x; cx[i].y = cx[i].y * sc + rv[rr][i].y;
              cx[i].z = cx[i].z * sc + rv[rr][i].z; cx[i].w = cx[i].w * sc + rv[rr][i].w;
            }
          }
        }
      }
      // rows 61..63 single
      for (int r = 61; r <= 63; ++r) {
        const float* row = mb + (size_t)r * 1024;
        float4 rv[4];
        float s = 0.f;
#pragma unroll
        for (int i = 0; i < 4; ++i) {
          rv[i] = *(const float4*)(row + (i * 64 + lane) * 4);
          s += rv[i].x * qv[i].x + rv[i].y * qv[i].y + rv[i].z * qv[i].z + rv[i].w * qv[i].w;
        }
#pragma unroll
        for (int off = 32; off; off >>= 1) s += __shfl_xor(s, off);
        s *= 0.03125f;
        if (s <= m_run + 8.f) {
          float e = __expf(s - m_run);
          l += e;
#pragma unroll
          for (int i = 0; i < 4; ++i) {
            cx[i].x += e * rv[i].x; cx[i].y += e * rv[i].y;
            cx[i].z += e * rv[i].z; cx[i].w += e * rv[i].w;
          }
        } else {
          float sc = __expf(m_run - s);
          m_run = s;
          l = l * sc + 1.f;
#pragma unroll
          for (int i = 0; i < 4; ++i) {
            cx[i].x = cx[i].x * sc + rv[i].x; cx[i].y = cx[i].y * sc + rv[i].y;
            cx[i].z = cx[i].z * sc + rv[i].z; cx[i].w = cx[i].w * sc + rv[i].w;
          }
        }
      }
      // store state
      float* st = attst + (size_t)b * 1032;
#pragma unroll
      for (int i = 0; i < 4; ++i)
        *(float4*)(st + (i * 64 + lane) * 4) = cx[i];
      if (lane == 0) { st[1024] = m_run; st[1025] = l; }
    }
  }
}

// ---------------- fused LSTM elementwise + attention finish ----------------
// One block per batch row b.
__global__ __launch_bounds__(256) void lstmfin_k(
    const float* __restrict__ gates, const float* __restrict__ c,
    const float* __restrict__ Qk, const float* __restrict__ attst,
    float* __restrict__ out_h, float* __restrict__ out_c,
    u16* __restrict__ ctxb)
{
  const int b = blockIdx.x;
  const int t = threadIdx.x;
  const int lane = t & 63, wv_id = t >> 6;
  const int p = t * 4;
  const float* g = gates + (size_t)b * 4096;
  float4 ig = *(const float4*)(g + p);
  float4 fg = *(const float4*)(g + 1024 + p);
  float4 gg = *(const float4*)(g + 2048 + p);
  float4 og = *(const float4*)(g + 3072 + p);
  float4 cv = *(const float4*)(c + (size_t)b * 1024 + p);

  float hn[4], cn[4];
  {
    float igs[4] = {ig.x, ig.y, ig.z, ig.w};
    float fgs[4] = {fg.x, fg.y, fg.z, fg.w};
    float ggs[4] = {gg.x, gg.y, gg.z, gg.w};
    float ogs[4] = {og.x, og.y, og.z, og.w};
    float cvs[4] = {cv.x, cv.y, cv.z, cv.w};
#pragma unroll
    for (int j = 0; j < 4; ++j) {
      float si = 1.f / (1.f + __expf(-igs[j]));
      float sf = 1.f / (1.f + __expf(-fgs[j]));
      float so = 1.f / (1.f + __expf(-ogs[j]));
      float tg = 2.f / (1.f + __expf(-2.f * ggs[j])) - 1.f;
      cn[j] = sf * cvs[j] + si * tg;
      float tc2 = 2.f / (1.f + __expf(-2.f * cn[j])) - 1.f;
      hn[j] = so * tc2;
    }
  }
  *(float4*)(out_c + (size_t)b * 1024 + p) = make_float4(cn[0], cn[1], cn[2], cn[3]);
  *(float4*)(out_h + (size_t)b * 1024 + p) = make_float4(hn[0], hn[1], hn[2], hn[3]);

  // s_last = dot(Qk[b], h_new[b]) / 32  (block reduction)
  float4 qv = *(const float4*)(Qk + (size_t)b * 1024 + p);
  float part = qv.x * hn[0] + qv.y * hn[1] + qv.z * hn[2] + qv.w * hn[3];
#pragma unroll
  for (int off = 32; off; off >>= 1) part += __shfl_xor(part, off);
  __shared__ float red[4];
  if (lane == 0) red[wv_id] = part;
  __syncthreads();
  float s_last = (red[0] + red[1] + red[2] + red[3]) * 0.03125f;

  // combine with online-softmax state, normalize, write bf16 ctx
  const float* st = attst + (size_t)b * 1032;
  float m_run = st[1024], l = st[1025];
  float4 cx = *(const float4*)(st + p);
  if (s_last <= m_run + 8.f) {
    float e = __expf(s_last - m_run);
    l += e;
    cx.x += e * hn[0]; cx.y += e * hn[1]; cx.z += e * hn[2]; cx.w += e * hn[3];
  } else {
    float sc = __expf(m_run - s_last);
    l = l * sc + 1.f;
    cx.x = cx.x * sc + hn[0]; cx.y = cx.y * sc + hn[1];
    cx.z = cx.z * sc + hn[2]; cx.w = cx.w * sc + hn[3];
  }
  float inv = 1.f / l;
  ushort4 o;
  o.x = f2bf(cx.x * inv); o.y = f2bf(cx.y * inv);
  o.z = f2bf(cx.z * inv); o.w = f2bf(cx.w * inv);
  *(ushort4*)(ctxb + (size_t)b * 1024 + p) = o;
}

extern "C" void kernel_launch(void* const* d_in, const int* in_sizes, int n_in,
                              void* d_out, int out_size, void* d_ws, size_t ws_size,
                              hipStream_t stream) {
  const int Bb = 2048, Hh = 1024;
  const float* pose  = (const float*)d_in[0];
  const float* query = (const float*)d_in[1];
  const float* h     = (const float*)d_in[2];
  const float* c     = (const float*)d_in[3];
  const float* mem   = (const float*)d_in[4];
  const float* W_ih  = (const float*)d_in[5];
  const float* W_hh  = (const float*)d_in[6];
  const float* b_ih  = (const float*)d_in[7];
  const float* b_hh  = (const float*)d_in[8];
  const float* Wq    = (const float*)d_in[9];
  const float* bq    = (const float*)d_in[10];
  const float* Wk    = (const float*)d_in[11];
  // d_in[12] = bk: m-independent score shift, cancels in softmax
  const float* Wv    = (const float*)d_in[13];
  const float* bv    = (const float*)d_in[14];

  float* out_att = (float*)d_out;
  float* out_h   = out_att + (size_t)Bb * Hh;
  float* out_c   = out_h + (size_t)Bb * Hh;

  char* wp = (char*)d_ws;
  auto alloc = [&](size_t bytes) {
    char* p = wp; wp += (bytes + 255) & ~(size_t)255; return p;
  };
  u16*   Xcat  = (u16*)alloc((size_t)2048 * 2048 * 2);   // 8 MB
  u16*   Wcat  = (u16*)alloc((size_t)4096 * 2048 * 2);   // 16 MB
  u16*   Qryb  = (u16*)alloc((size_t)2048 * 1024 * 2);   // 4 MB  (dead after Q gemm)
  u16*   Wqb   = (u16*)alloc((size_t)1024 * 1024 * 2);   // 2 MB  (dead after Q gemm)
  u16*   WkTb  = (u16*)alloc((size_t)1024 * 1024 * 2);   // 2 MB  (dead after Qk gemm)
  u16*   Qbf   = (u16*)alloc((size_t)2048 * 1024 * 2);   // 4 MB  (dead after Qk gemm)
  u16*   Wvb   = (u16*)alloc((size_t)1024 * 1024 * 2);   // 2 MB
  float* gates = (float*)alloc((size_t)2048 * 4096 * 4); // 32 MB
  float* Qk    = (float*)alloc((size_t)2048 * 1024 * 4); // 8 MB
  u16*   ctxb  = (u16*)alloc((size_t)2048 * 1024 * 2);   // 4 MB
  // attst aliases the dead-after-QkGEMM region (Qryb..Qbf = 12 MB > 8.5 MB)
  float* attst = (float*)Qryb;                            // [2048][1032] f32

  // 1. all conversions in one kernel
  prep_k<<<16640, 256, 0, stream>>>(pose, h, W_ih, W_hh, query, Wv, Wq, Wk,
                                    Xcat, Wcat, Qryb, Wvb, Wqb, WkTb);

  // 2. Q = query @ Wq^T + bq  (bf16)
  gemm_bt<<<dim3(8, 16), 256, 0, stream>>>(
      Qryb, Wqb, nullptr, Qbf, bq, 2048, 1024, 1024);

  // 3. Qk = Q @ Wk  (f32; bk cancels in softmax)
  gemm_bt<<<dim3(8, 16), 256, 0, stream>>>(
      Qbf, WkTb, Qk, nullptr, nullptr, 2048, 1024, 1024);

  // 4. mega: gates GEMM (512 tiles) || attention partial (256 blocks)
  mega_k<<<768, 256, 0, stream>>>(Xcat, Wcat, gates, b_ih, b_hh, Qk, mem, attst);

  // 5. LSTM elementwise + attention finish (h_new row) -> ctx bf16
  lstmfin_k<<<2048, 256, 0, stream>>>(gates, c, Qk, attst, out_h, out_c, ctxb);

  // 6. attended = ctx @ Wv^T + bv
  gemm_bt<<<dim3(8, 16), 256, 0, stream>>>(
      ctxb, Wvb, out_att, nullptr, bv, 2048, 1024, 1024);
}